// Round 5
// baseline (62.492 us; speedup 1.0000x reference)
//
#include <hip/hip_runtime.h>

// ColorReducer: per-pixel argmin_k of d2 = (x2 - 2.0f*cross) + p2 with the
// EXACT verified expression tree (R0/R2/R3 passed, absmax 0.0):
//   cross = ((r*pr + g*pg) + b*pb), x2 = ((r*r + g*g) + b*b),
//   d2 = (x2 - 2.0f*cross) + p2, +inf seed, strict < (np.argmin tie-break).
// DO NOT touch the math (R1 changed the tree and flipped labels).
//
// R4 = R0 structure (best: 4 px/thread, 4096 blocks, 2 launch generations)
// + ONE change: palette & p2 hoisted to SGPRs via readfirstlane
// (bit-transparent; palette is lane-uniform). R0's unrolled loop held 48
// palette floats + 16 p2 in VGPRs (~90 VGPR -> 4 waves/SIMD per m69 cliff);
// SGPR-hoisting + __launch_bounds__(256,8) targets 8 waves/SIMD.

constexpr int HW    = 512 * 512;   // 2^18
constexpr int KCOL  = 16;
constexpr long NPIX = 16L * HW;    // 4,194,304
constexpr int PPT   = 4;           // pixels per thread (one float4 per plane)

__device__ __forceinline__ float uni(float v) {
    // readfirstlane: bit-transparent for lane-uniform values; forces SGPR.
    return __int_as_float(__builtin_amdgcn_readfirstlane(__float_as_int(v)));
}

__global__ __launch_bounds__(256, 8) void color_reduce_kernel(
    const float* __restrict__ x,       // (B, 3, H, W)
    const float* __restrict__ pal,     // (16, 3)
    float* __restrict__ out)           // (B, 3, H, W)
{
    __shared__ float spal[KCOL * 3];
    if (threadIdx.x < KCOL * 3) spal[threadIdx.x] = pal[threadIdx.x];
    __syncthreads();

    // Palette -> SGPRs (uniform across lanes; readfirstlane is identity).
    float spr[KCOL], spg[KCOL], spb[KCOL], sp2[KCOL];
#pragma unroll
    for (int k = 0; k < KCOL; ++k) {
        spr[k] = uni(pal[3 * k + 0]);
        spg[k] = uni(pal[3 * k + 1]);
        spb[k] = uni(pal[3 * k + 2]);
        // p2 with the EXACT R0 expression; result re-hoisted to SGPR.
        sp2[k] = uni(__fadd_rn(__fadd_rn(__fmul_rn(spr[k], spr[k]),
                                         __fmul_rn(spg[k], spg[k])),
                               __fmul_rn(spb[k], spb[k])));
    }

    const long t  = (long)blockIdx.x * blockDim.x + threadIdx.x;
    const long n0 = t * PPT;
    const int b   = (int)(n0 >> 18);        // n0 / HW
    const int pix = (int)(n0 & (HW - 1));   // n0 % HW

    const float* base = x + (size_t)b * 3 * HW + pix;
    const float4 rv = *reinterpret_cast<const float4*>(base);
    const float4 gv = *reinterpret_cast<const float4*>(base + HW);
    const float4 bv = *reinterpret_cast<const float4*>(base + 2 * HW);

    float r[4]  = {rv.x, rv.y, rv.z, rv.w};
    float g[4]  = {gv.x, gv.y, gv.z, gv.w};
    float bl[4] = {bv.x, bv.y, bv.z, bv.w};

    float x2[4], best[4];
    int bestk[4];
#pragma unroll
    for (int i = 0; i < 4; ++i) {
        x2[i] = __fadd_rn(__fadd_rn(__fmul_rn(r[i], r[i]),
                                    __fmul_rn(g[i], g[i])),
                          __fmul_rn(bl[i], bl[i]));
        best[i]  = 3.4e38f;
        bestk[i] = 0;
    }

#pragma unroll
    for (int k = 0; k < KCOL; ++k) {
        const float pr = spr[k];   // SGPR operands (<=1 per VALU op)
        const float pg = spg[k];
        const float pb = spb[k];
        const float p2 = sp2[k];
#pragma unroll
        for (int i = 0; i < 4; ++i) {
            const float cross = __fadd_rn(__fadd_rn(__fmul_rn(r[i], pr),
                                                    __fmul_rn(g[i], pg)),
                                          __fmul_rn(bl[i], pb));
            const float d2 = __fadd_rn(__fsub_rn(x2[i], __fmul_rn(2.0f, cross)),
                                       p2);
            if (d2 < best[i]) { best[i] = d2; bestk[i] = k; }  // strict <
        }
    }

    float orr[4], ogg[4], obb[4];
#pragma unroll
    for (int i = 0; i < 4; ++i) {
        orr[i] = spal[3 * bestk[i] + 0];
        ogg[i] = spal[3 * bestk[i] + 1];
        obb[i] = spal[3 * bestk[i] + 2];
    }

    float* ob = out + (size_t)b * 3 * HW + pix;
    *reinterpret_cast<float4*>(ob)          = make_float4(orr[0], orr[1], orr[2], orr[3]);
    *reinterpret_cast<float4*>(ob + HW)     = make_float4(ogg[0], ogg[1], ogg[2], ogg[3]);
    *reinterpret_cast<float4*>(ob + 2 * HW) = make_float4(obb[0], obb[1], obb[2], obb[3]);
}

extern "C" void kernel_launch(void* const* d_in, const int* in_sizes, int n_in,
                              void* d_out, int out_size, void* d_ws, size_t ws_size,
                              hipStream_t stream) {
    const float* x   = (const float*)d_in[0];
    const float* pal = (const float*)d_in[1];
    float* out       = (float*)d_out;

    const int threads = 256;
    const long total_threads = NPIX / PPT;              // 1,048,576
    const int blocks = (int)(total_threads / threads);  // 4096
    color_reduce_kernel<<<blocks, threads, 0, stream>>>(x, pal, out);
}

// Round 6
// 23.574 us; speedup vs baseline: 2.6508x; 2.6508x over previous
//
#include <hip/hip_runtime.h>

// ColorReducer: per-pixel argmin_k of d2 = (x2 - 2*cross) + p2, bit-exact vs
// the numpy reference: cross = ((r*pr + g*pg) + b*pb), x2 = ((r*r+g*g)+b*b),
// d2 = (x2 - 2*cross) + p2, first-index tie-break (strict <).
//
// Exactness notes (all verified transformations):
//  - #pragma clang fp contract(off): no mul+add fusion -> plain ops are the
//    same RN ops the __f*_rn intrinsics gave R0 (absmax 0.0).
//  - pre-doubled pixels: fl(2r*pr)=2*fl(r*pr), fl(2x+2y)=2*fl(x+y) (exponent
//    shifts are exact) -> ((2r*pr+2g*pg)+2b*pb) == 2*cross bitwise.
//  - k=0 seed == +inf seed + strict < (identical winner).
//  - packed float2 ops are per-element IEEE RN == scalar (v_pk_* on CDNA).
// BANNED: __builtin_nontemporal_store (R1: stale output lines vs harness
// readback, absmax 0.611). Plain float4 stores only.
// BANNED: readfirstlane palette hoist + launch_bounds(,8) (R4: VGPR=32,
// scratch traffic 3x, 62 us).
//
// Structure = R0 (best, 26.0 us): 4 px/thread, 4096 blocks x 256 threads.
// R5 change: packed-f32 arithmetic (halves distance-pipeline issue count).

typedef float v2f __attribute__((ext_vector_type(2)));

constexpr int HW    = 512 * 512;   // 2^18
constexpr int KCOL  = 16;
constexpr long NPIX = 16L * HW;    // 4,194,304
constexpr int PPT   = 4;

__global__ __launch_bounds__(256) void color_reduce_kernel(
    const float* __restrict__ x,       // (B, 3, H, W)
    const float* __restrict__ pal,     // (16, 3)
    float* __restrict__ out)           // (B, 3, H, W)
{
#pragma clang fp contract(off)
    __shared__ float spal[KCOL * 3];
    if (threadIdx.x < KCOL * 3) spal[threadIdx.x] = pal[threadIdx.x];
    __syncthreads();

    const long t  = (long)blockIdx.x * blockDim.x + threadIdx.x;
    const long n0 = t * PPT;
    const int b   = (int)(n0 >> 18);        // n0 / HW
    const int pix = (int)(n0 & (HW - 1));   // n0 % HW

    const float* base = x + (size_t)b * 3 * HW + pix;
    const float4 rv = *reinterpret_cast<const float4*>(base);
    const float4 gv = *reinterpret_cast<const float4*>(base + HW);
    const float4 bv = *reinterpret_cast<const float4*>(base + 2 * HW);

    // Pixel pairs as packed f32.
    const v2f rA = {rv.x, rv.y}, rB = {rv.z, rv.w};
    const v2f gA = {gv.x, gv.y}, gB = {gv.z, gv.w};
    const v2f bA = {bv.x, bv.y}, bB = {bv.z, bv.w};

    // x2 = ((r*r + g*g) + b*b)  [exact reference tree, packed]
    const v2f x2A = ((rA * rA) + (gA * gA)) + (bA * bA);
    const v2f x2B = ((rB * rB) + (gB * gB)) + (bB * bB);

    // Pre-doubled pixels (exact: fl(r+r) = 2r).
    const v2f r2A = rA + rA, g2A = gA + gA, b2A = bA + bA;
    const v2f r2B = rB + rB, g2B = gB + gB, b2B = bB + bB;

    float best0, best1, best2, best3;
    int   k0 = 0, k1 = 0, k2 = 0, k3 = 0;

    {   // k = 0 seeds best (== +inf seed with strict <)
        const float pr = pal[0], pg = pal[1], pb = pal[2];
        const float p2 = ((pr * pr) + (pg * pg)) + (pb * pb);
        const v2f prv = {pr, pr}, pgv = {pg, pg}, pbv = {pb, pb}, p2v = {p2, p2};
        const v2f crA = ((r2A * prv) + (g2A * pgv)) + (b2A * pbv);  // == 2*cross
        const v2f crB = ((r2B * prv) + (g2B * pgv)) + (b2B * pbv);
        const v2f dA  = (x2A - crA) + p2v;                          // exact d2
        const v2f dB  = (x2B - crB) + p2v;
        best0 = dA.x; best1 = dA.y; best2 = dB.x; best3 = dB.y;
    }

#pragma unroll
    for (int k = 1; k < KCOL; ++k) {
        const float pr = pal[3 * k + 0];   // uniform -> s_load/SGPR
        const float pg = pal[3 * k + 1];
        const float pb = pal[3 * k + 2];
        const float p2 = ((pr * pr) + (pg * pg)) + (pb * pb);
        const v2f prv = {pr, pr}, pgv = {pg, pg}, pbv = {pb, pb}, p2v = {p2, p2};
        const v2f crA = ((r2A * prv) + (g2A * pgv)) + (b2A * pbv);
        const v2f crB = ((r2B * prv) + (g2B * pgv)) + (b2B * pbv);
        const v2f dA  = (x2A - crA) + p2v;
        const v2f dB  = (x2B - crB) + p2v;
        if (dA.x < best0) { best0 = dA.x; k0 = k; }   // strict <: np.argmin
        if (dA.y < best1) { best1 = dA.y; k1 = k; }
        if (dB.x < best2) { best2 = dB.x; k2 = k; }
        if (dB.y < best3) { best3 = dB.y; k3 = k; }
    }

    const int bk[4] = {k0, k1, k2, k3};
    float orr[4], ogg[4], obb[4];
#pragma unroll
    for (int i = 0; i < 4; ++i) {
        orr[i] = spal[3 * bk[i] + 0];
        ogg[i] = spal[3 * bk[i] + 1];
        obb[i] = spal[3 * bk[i] + 2];
    }

    float* ob = out + (size_t)b * 3 * HW + pix;
    *reinterpret_cast<float4*>(ob)          = make_float4(orr[0], orr[1], orr[2], orr[3]);
    *reinterpret_cast<float4*>(ob + HW)     = make_float4(ogg[0], ogg[1], ogg[2], ogg[3]);
    *reinterpret_cast<float4*>(ob + 2 * HW) = make_float4(obb[0], obb[1], obb[2], obb[3]);
}

extern "C" void kernel_launch(void* const* d_in, const int* in_sizes, int n_in,
                              void* d_out, int out_size, void* d_ws, size_t ws_size,
                              hipStream_t stream) {
    const float* x   = (const float*)d_in[0];
    const float* pal = (const float*)d_in[1];
    float* out       = (float*)d_out;

    const int threads = 256;
    const long total_threads = NPIX / PPT;              // 1,048,576
    const int blocks = (int)(total_threads / threads);  // 4096
    color_reduce_kernel<<<blocks, threads, 0, stream>>>(x, pal, out);
}